// Round 1
// baseline (823.862 us; speedup 1.0000x reference)
//
#include <hip/hip_runtime.h>

#define IN_F   128
#define OUT_F  64
#define RB     32    // rows per GEMM block

// ---------------- GEMM: out[n,o] = sum_k x[n,k]*W[o,k] + b[o] ----------------
__global__ __launch_bounds__(256) void gemm_kernel(
    const float* __restrict__ x, const float* __restrict__ W,
    const float* __restrict__ b, float* __restrict__ out, int N) {
    __shared__ float xs[RB][IN_F + 4];     // +4 keeps float4 align, breaks bank stride
    __shared__ float Ws[OUT_F][IN_F + 4];

    const int t = threadIdx.x;
    const int row0 = blockIdx.x * RB;

    // stage W: 64*128 floats = 2048 float4, 256 threads -> 8 iters
    for (int i = t; i < OUT_F * IN_F / 4; i += 256) {
        int f = i >> 5;              // /(IN_F/4)
        int k = (i & 31) << 2;
        float4 v = ((const float4*)W)[i];
        *(float4*)&Ws[f][k] = v;
    }
    // stage x rows: 32*128 floats = 1024 float4 -> 4 iters
    for (int i = t; i < RB * IN_F / 4; i += 256) {
        int r = i >> 5;
        int k = (i & 31) << 2;
        int gr = row0 + r;
        float4 v = make_float4(0.f, 0.f, 0.f, 0.f);
        if (gr < N) v = ((const float4*)x)[(size_t)gr * (IN_F / 4) + (i & 31)];
        *(float4*)&xs[r][k] = v;
    }
    __syncthreads();

    // each thread: 2 consecutive feats x 4 rows
    const int fpair = (t & 31) * 2;
    const int rg = t >> 5;           // 0..7
    float acc[4][2] = {};
    #pragma unroll
    for (int k = 0; k < IN_F; k += 4) {
        float4 w0 = *(float4*)&Ws[fpair][k];
        float4 w1 = *(float4*)&Ws[fpair + 1][k];
        #pragma unroll
        for (int j = 0; j < 4; ++j) {
            float4 xv = *(float4*)&xs[rg + j * 8][k];
            acc[j][0] += xv.x * w0.x + xv.y * w0.y + xv.z * w0.z + xv.w * w0.w;
            acc[j][1] += xv.x * w1.x + xv.y * w1.y + xv.z * w1.z + xv.w * w1.w;
        }
    }
    #pragma unroll
    for (int j = 0; j < 4; ++j) {
        int gr = row0 + rg + j * 8;
        if (gr < N) {
            out[(size_t)gr * OUT_F + fpair]     = acc[j][0] + b[fpair];
            out[(size_t)gr * OUT_F + fpair + 1] = acc[j][1] + b[fpair + 1];
        }
    }
}

// ---------------- SPMM: out[row[e]] += attr[e] * in[col[e]] ----------------
// one wave per edge, lane = feature (OUT_F==64 == wave size)
__global__ __launch_bounds__(256) void spmm_kernel(
    const int* __restrict__ rowi, const int* __restrict__ coli,
    const float* __restrict__ attr, const float* __restrict__ in,
    float* __restrict__ out, int E) {
    int tid = blockIdx.x * 256 + threadIdx.x;
    int e = tid >> 6;
    int lane = tid & 63;
    if (e >= E) return;
    int r = rowi[e];          // wave-uniform -> scalar load
    int c = coli[e];
    float w = attr[e];
    float v = in[(size_t)c * OUT_F + lane];
    atomicAdd(&out[(size_t)r * OUT_F + lane], w * v);
}

extern "C" void kernel_launch(void* const* d_in, const int* in_sizes, int n_in,
                              void* d_out, int out_size, void* d_ws, size_t ws_size,
                              hipStream_t stream) {
    const float* x    = (const float*)d_in[0];
    const int*   ei   = (const int*)d_in[1];    // [2, E] int32 per harness contract
    const float* attr = (const float*)d_in[2];
    const float* W    = (const float*)d_in[3];
    const float* b    = (const float*)d_in[4];
    float* out = (float*)d_out;
    float* ws0 = (float*)d_ws;

    const int N = in_sizes[0] / IN_F;   // 50000
    const int E = in_sizes[2];          // 800000
    const int* rowi = ei;
    const int* coli = ei + E;

    const size_t obytes = (size_t)N * OUT_F * sizeof(float);
    const int spmm_blocks = (E * 64 + 255) / 256;   // E/4

    // out0 = x @ W^T + b  -> ws0
    gemm_kernel<<<(N + RB - 1) / RB, 256, 0, stream>>>(x, W, b, ws0, N);

    // round 1: ws0 -> out
    hipMemsetAsync(out, 0, obytes, stream);
    spmm_kernel<<<spmm_blocks, 256, 0, stream>>>(rowi, coli, attr, ws0, out, E);

    // round 2: out -> ws0
    hipMemsetAsync(ws0, 0, obytes, stream);
    spmm_kernel<<<spmm_blocks, 256, 0, stream>>>(rowi, coli, attr, out, ws0, E);

    // round 3: ws0 -> out
    hipMemsetAsync(out, 0, obytes, stream);
    spmm_kernel<<<spmm_blocks, 256, 0, stream>>>(rowi, coli, attr, ws0, out, E);
}

// Round 2
// 313.649 us; speedup vs baseline: 2.6267x; 2.6267x over previous
//
#include <hip/hip_runtime.h>

#define IN_F   128
#define OUT_F  64
#define GR     64    // rows per GEMM block

// ---------------- GEMM: out[n,o] = sum_k x[n,k]*W[o,k] + b[o] ----------------
// 64x64 tile; thread = 4 rows x 4 feats; Wt transposed in LDS for conflict-free reads.
__global__ __launch_bounds__(256) void gemm_kernel(
    const float* __restrict__ x, const float* __restrict__ W,
    const float* __restrict__ b, float* __restrict__ out, int N) {
    __shared__ float xs[GR][IN_F + 4];        // 64 x 132  (33.8 KB)
    __shared__ float Wt[IN_F][OUT_F + 4];     // 128 x 68  (34.8 KB) transposed

    const int t = threadIdx.x;
    const int row0 = blockIdx.x * GR;

    // stage W transposed: i -> (o = i&63, c = i>>6); LDS writes conflict-free (o fast)
    for (int i = t; i < OUT_F * (IN_F / 4); i += 256) {
        int o = i & 63;
        int c = i >> 6;                       // k-chunk 0..31
        float4 v = ((const float4*)W)[o * (IN_F / 4) + c];
        Wt[4 * c + 0][o] = v.x;
        Wt[4 * c + 1][o] = v.y;
        Wt[4 * c + 2][o] = v.z;
        Wt[4 * c + 3][o] = v.w;
    }
    // stage x rows (coalesced): i -> (r = i>>5, c = i&31)
    for (int i = t; i < GR * (IN_F / 4); i += 256) {
        int r = i >> 5, c = i & 31;
        int gr = row0 + r;
        float4 v = make_float4(0.f, 0.f, 0.f, 0.f);
        if (gr < N) v = ((const float4*)x)[(size_t)gr * (IN_F / 4) + c];
        *(float4*)&xs[r][4 * c] = v;
    }
    __syncthreads();

    const int f0 = (t & 15) * 4;              // 4 consecutive feats
    const int r0 = (t >> 4) * 4;              // 4 consecutive rows
    float acc[4][4] = {};

    #pragma unroll 2                          // DO NOT fully unroll: R1 spilled at 256 VGPR
    for (int k = 0; k < IN_F; k += 4) {
        float4 xv[4], wv[4];
        #pragma unroll
        for (int i = 0; i < 4; ++i) xv[i] = *(const float4*)&xs[r0 + i][k];
        #pragma unroll
        for (int j = 0; j < 4; ++j) wv[j] = *(const float4*)&Wt[k + j][f0];
        #pragma unroll
        for (int i = 0; i < 4; ++i) {
            acc[i][0] += xv[i].x * wv[0].x + xv[i].y * wv[1].x + xv[i].z * wv[2].x + xv[i].w * wv[3].x;
            acc[i][1] += xv[i].x * wv[0].y + xv[i].y * wv[1].y + xv[i].z * wv[2].y + xv[i].w * wv[3].y;
            acc[i][2] += xv[i].x * wv[0].z + xv[i].y * wv[1].z + xv[i].z * wv[2].z + xv[i].w * wv[3].z;
            acc[i][3] += xv[i].x * wv[0].w + xv[i].y * wv[1].w + xv[i].z * wv[2].w + xv[i].w * wv[3].w;
        }
    }

    float4 bv = *(const float4*)&b[f0];
    #pragma unroll
    for (int i = 0; i < 4; ++i) {
        int gr = row0 + r0 + i;
        if (gr < N) {
            float4 o4 = make_float4(acc[i][0] + bv.x, acc[i][1] + bv.y,
                                    acc[i][2] + bv.z, acc[i][3] + bv.w);
            *(float4*)&out[(size_t)gr * OUT_F + f0] = o4;
        }
    }
}

// ---------------- CSR build ----------------
__global__ __launch_bounds__(256) void hist_kernel(const int* __restrict__ rowi,
                                                   int* __restrict__ counts, int E) {
    int e = blockIdx.x * 256 + threadIdx.x;
    if (e < E) atomicAdd(&counts[rowi[e]], 1);
}

__global__ __launch_bounds__(256) void scan1_kernel(const int* __restrict__ counts,
                                                    int* __restrict__ rowptr,
                                                    int* __restrict__ bsums, int N) {
    int tid = threadIdx.x, gid = blockIdx.x * 256 + tid;
    int lane = tid & 63, w = tid >> 6;
    int v = (gid < N) ? counts[gid] : 0;
    int sum = v;
    #pragma unroll
    for (int off = 1; off < 64; off <<= 1) {
        int tt = __shfl_up(sum, off, 64);
        if (lane >= off) sum += tt;
    }
    __shared__ int wsum[4];
    if (lane == 63) wsum[w] = sum;
    __syncthreads();
    int woff = 0;
    for (int i = 0; i < w; ++i) woff += wsum[i];
    int incl = sum + woff;
    if (gid < N) rowptr[gid] = incl - v;      // block-local exclusive
    if (tid == 255) bsums[blockIdx.x] = incl; // block total
}

__global__ __launch_bounds__(256) void scan2_kernel(int* __restrict__ bsums, int nb) {
    int tid = threadIdx.x;
    int lane = tid & 63, w = tid >> 6;
    int v = (tid < nb) ? bsums[tid] : 0;
    int sum = v;
    #pragma unroll
    for (int off = 1; off < 64; off <<= 1) {
        int tt = __shfl_up(sum, off, 64);
        if (lane >= off) sum += tt;
    }
    __shared__ int wsum[4];
    if (lane == 63) wsum[w] = sum;
    __syncthreads();
    int woff = 0;
    for (int i = 0; i < w; ++i) woff += wsum[i];
    if (tid < nb) bsums[tid] = sum + woff - v; // exclusive
}

__global__ __launch_bounds__(256) void scan3_kernel(int* __restrict__ rowptr,
                                                    const int* __restrict__ bsums,
                                                    int N, int E) {
    int gid = blockIdx.x * 256 + threadIdx.x;
    if (gid < N) rowptr[gid] += bsums[blockIdx.x];
    if (gid == 0) rowptr[N] = E;
}

__global__ __launch_bounds__(256) void scatter_kernel(
    const int* __restrict__ rowi, const int* __restrict__ coli,
    const float* __restrict__ attr, const int* __restrict__ rowptr,
    int* __restrict__ cursor, int* __restrict__ scol, float* __restrict__ sval, int E) {
    int e = blockIdx.x * 256 + threadIdx.x;
    if (e >= E) return;
    int r = rowi[e];
    int p = rowptr[r] + atomicAdd(&cursor[r], 1);
    scol[p] = coli[e];
    sval[p] = attr[e];
}

// ---------------- SPMM (CSR, no atomics): wave per row, lane = feature ----------------
__global__ __launch_bounds__(256) void spmm_csr_kernel(
    const int* __restrict__ rowptr, const int* __restrict__ scol,
    const float* __restrict__ sval, const float* __restrict__ in,
    float* __restrict__ out, int N) {
    int wid = (blockIdx.x * 256 + threadIdx.x) >> 6;
    int lane = threadIdx.x & 63;
    if (wid >= N) return;
    int beg = rowptr[wid], end = rowptr[wid + 1];
    float acc = 0.f;
    int e = beg;
    for (; e + 4 <= end; e += 4) {
        int c0 = scol[e + 0], c1 = scol[e + 1], c2 = scol[e + 2], c3 = scol[e + 3];
        float v0 = sval[e + 0], v1 = sval[e + 1], v2 = sval[e + 2], v3 = sval[e + 3];
        float x0 = in[(size_t)c0 * OUT_F + lane];
        float x1 = in[(size_t)c1 * OUT_F + lane];
        float x2 = in[(size_t)c2 * OUT_F + lane];
        float x3 = in[(size_t)c3 * OUT_F + lane];
        acc += v0 * x0; acc += v1 * x1; acc += v2 * x2; acc += v3 * x3;
    }
    for (; e < end; ++e) acc += sval[e] * in[(size_t)scol[e] * OUT_F + lane];
    out[(size_t)wid * OUT_F + lane] = acc;
}

// ---------------- fallback SPMM (atomics) if ws too small ----------------
__global__ __launch_bounds__(256) void spmm_atomic_kernel(
    const int* __restrict__ rowi, const int* __restrict__ coli,
    const float* __restrict__ attr, const float* __restrict__ in,
    float* __restrict__ out, int E) {
    int tid = blockIdx.x * 256 + threadIdx.x;
    int e = tid >> 6;
    int lane = tid & 63;
    if (e >= E) return;
    int r = rowi[e];
    int c = coli[e];
    float w = attr[e];
    float v = in[(size_t)c * OUT_F + lane];
    atomicAdd(&out[(size_t)r * OUT_F + lane], w * v);
}

extern "C" void kernel_launch(void* const* d_in, const int* in_sizes, int n_in,
                              void* d_out, int out_size, void* d_ws, size_t ws_size,
                              hipStream_t stream) {
    const float* x    = (const float*)d_in[0];
    const int*   ei   = (const int*)d_in[1];    // [2, E] int32 (confirmed R1)
    const float* attr = (const float*)d_in[2];
    const float* W    = (const float*)d_in[3];
    const float* b    = (const float*)d_in[4];
    float* out = (float*)d_out;

    const int N = in_sizes[0] / IN_F;   // 50000
    const int E = in_sizes[2];          // 800000
    const int* rowi = ei;
    const int* coli = ei + E;

    const size_t obytes = (size_t)N * OUT_F * sizeof(float);

    // ---- ws layout ----
    char* wp = (char*)d_ws;
    size_t off = 0;
    auto alloc = [&](size_t bytes) { char* p = wp + off; off += (bytes + 255) & ~(size_t)255; return p; };
    float* ws0    = (float*)alloc(obytes);                    // ping-pong buffer
    int*   rowptr = (int*)  alloc((size_t)(N + 1) * 4);
    int*   counts = (int*)  alloc((size_t)N * 4);
    int*   cursor = (int*)  alloc((size_t)N * 4);
    int*   bsums  = (int*)  alloc(256 * 4);
    int*   scol   = (int*)  alloc((size_t)E * 4);
    float* sval   = (float*)alloc((size_t)E * 4);
    const bool csr_ok = (off <= ws_size);

    const int gemm_blocks = (N + GR - 1) / GR;
    const int eb = (E + 255) / 256;              // edge-parallel blocks
    const int nb = (N + 255) / 256;              // 196 scan blocks (fits scan2's 256)

    // out0 = x @ W^T + b  -> ws0
    gemm_kernel<<<gemm_blocks, 256, 0, stream>>>(x, W, b, ws0, N);

    if (csr_ok) {
        // ---- build CSR (row-sorted) ----
        hipMemsetAsync(counts, 0, (size_t)N * 4, stream);
        hipMemsetAsync(cursor, 0, (size_t)N * 4, stream);
        hist_kernel<<<eb, 256, 0, stream>>>(rowi, counts, E);
        scan1_kernel<<<nb, 256, 0, stream>>>(counts, rowptr, bsums, N);
        scan2_kernel<<<1, 256, 0, stream>>>(bsums, nb);
        scan3_kernel<<<nb, 256, 0, stream>>>(rowptr, bsums, N, E);
        scatter_kernel<<<eb, 256, 0, stream>>>(rowi, coli, attr, rowptr, cursor, scol, sval, E);

        // ---- 3 rounds, no atomics, no output memsets (every row written) ----
        const int sb = (N * 64 + 255) / 256;
        spmm_csr_kernel<<<sb, 256, 0, stream>>>(rowptr, scol, sval, ws0, out, N);
        spmm_csr_kernel<<<sb, 256, 0, stream>>>(rowptr, scol, sval, out, ws0, N);
        spmm_csr_kernel<<<sb, 256, 0, stream>>>(rowptr, scol, sval, ws0, out, N);
    } else {
        // fallback: R1 edge-parallel atomic path
        const int spmm_blocks = (E * 64 + 255) / 256;
        hipMemsetAsync(out, 0, obytes, stream);
        spmm_atomic_kernel<<<spmm_blocks, 256, 0, stream>>>(rowi, coli, attr, ws0, out, E);
        hipMemsetAsync(ws0, 0, obytes, stream);
        spmm_atomic_kernel<<<spmm_blocks, 256, 0, stream>>>(rowi, coli, attr, out, ws0, E);
        hipMemsetAsync(out, 0, obytes, stream);
        spmm_atomic_kernel<<<spmm_blocks, 256, 0, stream>>>(rowi, coli, attr, ws0, out, E);
    }
}